// Round 1
// baseline (46.605 us; speedup 1.0000x reference)
//
#include <hip/hip_runtime.h>

#define HH 160
#define WW 160
#define CC 32
#define NN 8

// One thread: fixed (n, h, w, channel-group). Computes 4 subpixel outputs for
// each of 8 channels. 64 lanes = consecutive w (coalesced loads/stores);
// threadIdx.x>>6 = channel group.
__global__ __launch_bounds__(256) void pixelconv_k(
    const float* __restrict__ feature,   // [8,32,160,160]
    const float* __restrict__ kern,      // [8,36,160,160]
    float* __restrict__ out)             // [8,32,320,320]
{
    const int wt = blockIdx.x;          // 0..2 (w tiles of 64)
    const int h  = blockIdx.y;          // 0..159
    const int n  = blockIdx.z;          // 0..7
    const int wl = threadIdx.x & 63;
    const int cg = threadIdx.x >> 6;    // 0..3
    const int w  = wt * 64 + wl;
    if (w >= WW) return;

    // Hoist the 36 per-pixel kernel values into registers (channel-invariant).
    // kern[n][j][h][w], j = k*4 + s, k = dx*3 + dy
    float kv[36];
    const float* kp = kern + (((size_t)n * 36) * HH + h) * WW + w;
    #pragma unroll
    for (int j = 0; j < 36; ++j)
        kv[j] = kp[(size_t)j * HH * WW];

    const bool hm = (h > 0), hp = (h < HH - 1);
    const bool wm = (w > 0), wp = (w < WW - 1);

    float* outn = out + (size_t)n * CC * (2 * HH) * (2 * WW);

    #pragma unroll
    for (int i = 0; i < 8; ++i) {
        const int c = cg * 8 + i;
        const float* fc = feature + ((size_t)(n * CC + c) * HH) * WW;

        // 9 feature taps, k = dx*3 + dy, value = feature[h+dy-1][w+dx-1]
        float f[9];
        #pragma unroll
        for (int dx = 0; dx < 3; ++dx) {
            #pragma unroll
            for (int dy = 0; dy < 3; ++dy) {
                const int hh = h + dy - 1;
                const int ww = w + dx - 1;
                const bool ok = (dy != 0 || hm) && (dy != 2 || hp) &&
                                (dx != 0 || wm) && (dx != 2 || wp);
                f[dx * 3 + dy] = ok ? fc[hh * WW + ww] : 0.0f;
            }
        }

        float a0 = 0.f, a1 = 0.f, a2 = 0.f, a3 = 0.f;
        #pragma unroll
        for (int k = 0; k < 9; ++k) {
            a0 = fmaf(f[k], kv[k * 4 + 0], a0);
            a1 = fmaf(f[k], kv[k * 4 + 1], a1);
            a2 = fmaf(f[k], kv[k * 4 + 2], a2);
            a3 = fmaf(f[k], kv[k * 4 + 3], a3);
        }

        // pixel shuffle: s = r1*2 + r2 -> out[2h+r1][2w+r2]; r2 contiguous.
        float* oc = outn + (size_t)c * (2 * HH) * (2 * WW);
        *(float2*)(oc + (size_t)(2 * h)     * (2 * WW) + 2 * w) = make_float2(a0, a1);
        *(float2*)(oc + (size_t)(2 * h + 1) * (2 * WW) + 2 * w) = make_float2(a2, a3);
    }
}

extern "C" void kernel_launch(void* const* d_in, const int* in_sizes, int n_in,
                              void* d_out, int out_size, void* d_ws, size_t ws_size,
                              hipStream_t stream) {
    const float* feature = (const float*)d_in[0];
    const float* kern    = (const float*)d_in[1];
    float* out           = (float*)d_out;

    dim3 grid((WW + 63) / 64, HH, NN);   // (3, 160, 8)
    pixelconv_k<<<grid, 256, 0, stream>>>(feature, kern, out);
}